// Round 8
// baseline (3233.092 us; speedup 1.0000x reference)
//
#include <hip/hip_runtime.h>
#include <cstdint>

// CharRNN 2-layer LSTM, B=32,T=256,H=1024,V=256. Persistent kernel, round 8:
//   wgs 0..127  = layer-0 chain (8 units each), Whh0 hi+lo frags in LDS
//   wgs 128..255= layer-1 chain (8 units each): waves 0,1 = CRITICAL h1@Whh1 (16 iters each),
//                 waves 2,3 = CONCURRENT prefetch zpre_{t+1}=h0_{t+1}@Wih1 (LDS double-buffer).
//   Flags PACKED (stride 4B): one poll iteration = 2 dword loads/lane = 8 cache lines total.
//   Projection: L0 wgs take early t (instant), L1 wgs late t; slow-sleep tail polls.
//   h slots write-once (257/layer); h0 slots 1..128 alias WA0; stores sc0sc1 write-through.
//   math: mfma_f32_16x16x32_bf16 split-bf16 (hi*hi + hi*lo + lo*hi) ~ f32 accuracy.

typedef float    f32x4 __attribute__((ext_vector_type(4)));
typedef short    s16x8 __attribute__((ext_vector_type(8)));
typedef unsigned u32x4 __attribute__((ext_vector_type(4)));

#define DEV __device__ __forceinline__

DEV unsigned short f2bf(float x){
  unsigned u = __builtin_bit_cast(unsigned, x);
  unsigned r = (u + 0x7fffu + ((u >> 16) & 1u)) >> 16;   // round-nearest-even
  return (unsigned short)r;
}
DEV float bf2f(unsigned short b){ return __builtin_bit_cast(float, ((unsigned)b) << 16); }

DEV s16x8 ld16(const void* p){ return *(const s16x8*)p; }

DEV f32x4 MF(s16x8 a, s16x8 b, f32x4 c){
  return __builtin_amdgcn_mfma_f32_16x16x32_bf16(a, b, c, 0, 0, 0);
}

// coherent (bypass L1/L2) 16B load — only for WA0/WAi0 (aliased regions)
#define LDC(dst, ptr)  asm volatile("global_load_dwordx4 %0, %1, off sc0 sc1" : "=v"(dst) : "v"(ptr))
// plain cached 16B load (participates in our vmcnt accounting)
#define LDP(dst, ptr)  asm volatile("global_load_dwordx4 %0, %1, off"         : "=v"(dst) : "v"(ptr))
#define WAITVM(n) do { asm volatile("s_waitcnt vmcnt(" #n ")" ::: "memory"); \
                       __builtin_amdgcn_sched_barrier(0); } while (0)
#define CFENCE()  asm volatile("" ::: "memory")
#define TRIPLE(Cmn, Ahm, Alm, Bhn, Bln) do { \
    Cmn = MF(Ahm, Bhn, Cmn); Cmn = MF(Ahm, Bln, Cmn); Cmn = MF(Alm, Bhn, Cmn); } while (0)

DEV void st16c(void* p, u32x4 v){   // coherent 16B store (write-through)
  asm volatile("global_store_dwordx4 %0, %1, off sc0 sc1" :: "v"(p), "v"(v) : "memory");
}
DEV void set_flag(int* p, int v){
  __hip_atomic_store(p, v, __ATOMIC_RELAXED, __HIP_MEMORY_SCOPE_AGENT);
}
// collective poll over PACKED flags (128 ints contiguous). 8 cache lines per iteration.
template<int SLP>
DEV void pollP(const int* f, int lane, int target){
  const int* p0 = f + lane;
  const int* p1 = f + 64 + lane;
  for (;;) {
    int a = __hip_atomic_load(p0, __ATOMIC_RELAXED, __HIP_MEMORY_SCOPE_AGENT);
    int b = __hip_atomic_load(p1, __ATOMIC_RELAXED, __HIP_MEMORY_SCOPE_AGENT);
    if (__all((a >= target) && (b >= target))) break;
    __builtin_amdgcn_s_sleep(SLP);
  }
  CFENCE();
}
// h0 slot address: 0 -> s0 buf; 1..128 -> aliased over WA0; 129..256 -> hi buf
DEV char* h0slot(char* wa0, char* s0, char* hi, int s){
  return (s == 0) ? s0 : ((s <= 128) ? wa0 + ((size_t)(s - 1) << 17)
                                     : hi  + ((size_t)(s - 129) << 17));
}

// ITERS-iteration half-GEMM: A hi from LDS (smemMat), A lo streamed from ALb, B from Bb
template<int ITERS>
DEV void halfgemmT(const char* smemMat, const char* ALb, const char* Bb,
                   int wgl, int ksb, int lane, f32x4 (&C)[2][2]) {
  s16x8 P[3][4], AL[3][2];
  #pragma unroll
  for (int d = 0; d < 2; ++d) {
    #pragma unroll
    for (int q = 0; q < 4; ++q) LDP(P[d][q], Bb + ((q * 32 + ksb + d) << 10) + lane * 16);
    LDP(AL[d][0], ALb + ((((wgl * 2 + 0) * 2 + 1) * 32 + ksb + d) << 10) + lane * 16);
    LDP(AL[d][1], ALb + ((((wgl * 2 + 1) * 2 + 1) * 32 + ksb + d) << 10) + lane * 16);
  }
  #pragma unroll
  for (int i = 0; i < ITERS; ++i) {
    const int ks = ksb + i;
    if (i < ITERS - 2) {
      #pragma unroll
      for (int q = 0; q < 4; ++q) LDP(P[(i + 2) % 3][q], Bb + ((q * 32 + ks + 2) << 10) + lane * 16);
      LDP(AL[(i + 2) % 3][0], ALb + ((((wgl * 2 + 0) * 2 + 1) * 32 + ks + 2) << 10) + lane * 16);
      LDP(AL[(i + 2) % 3][1], ALb + ((((wgl * 2 + 1) * 2 + 1) * 32 + ks + 2) << 10) + lane * 16);
    }
    s16x8 Ah0 = ld16(smemMat + ((0 * 32 + ks) << 10) + lane * 16);
    s16x8 Ah1 = ld16(smemMat + ((1 * 32 + ks) << 10) + lane * 16);
    if (i < ITERS - 2) { WAITVM(12); } else if (i == ITERS - 2) { WAITVM(6); } else { WAITVM(0); }
    TRIPLE(C[0][0], Ah0, AL[i % 3][0], P[i % 3][0], P[i % 3][2]);
    TRIPLE(C[0][1], Ah0, AL[i % 3][0], P[i % 3][1], P[i % 3][3]);
    TRIPLE(C[1][0], Ah1, AL[i % 3][1], P[i % 3][0], P[i % 3][2]);
    TRIPLE(C[1][1], Ah1, AL[i % 3][1], P[i % 3][1], P[i % 3][3]);
  }
}

// ---------------- prep: W[k][g*H+u] -> A-frag hi/lo bf16 [jb256][part2][ks32][64*16B] ----
__global__ void prep_wfrag(const float* __restrict__ W0, const float* __restrict__ W1,
                           const float* __restrict__ W2, const float* __restrict__ W3,
                           char* D0, char* D1, char* D2, char* D3) {
  int gid = blockIdx.x * 256 + threadIdx.x;       // 4*256*32*64 = 2M
  int lane = gid & 63, ks = (gid >> 6) & 31, jb = (gid >> 11) & 255, mat = gid >> 19;
  const float* S = (mat == 0) ? W0 : (mat == 1) ? W1 : (mat == 2) ? W2 : W3;
  char* D = (mat == 0) ? D0 : (mat == 1) ? D1 : (mat == 2) ? D2 : D3;
  int jp = jb * 16 + (lane & 15), u = jp >> 2, g = jp & 3;
  int kb = ks * 32 + (lane >> 4) * 8;
  s16x8 vh, vl;
  #pragma unroll
  for (int i = 0; i < 8; ++i) {
    float x = S[(kb + i) * 4096 + g * 1024 + u];
    unsigned short h = f2bf(x);
    vh[i] = (short)h;
    vl[i] = (short)f2bf(x - bf2f(h));
  }
  *(s16x8*)(D + (((jb * 2 + 0) * 32 + ks) << 10) + lane * 16) = vh;
  *(s16x8*)(D + (((jb * 2 + 1) * 32 + ks) << 10) + lane * 16) = vl;
}

// ---------------- prep: emb [v][k] and W_out [k][v] -> B-frag hi/lo [vb16][part2][ks32] ----
__global__ void prep_bfrag(const float* __restrict__ emb, const float* __restrict__ Wout,
                           char* Demb, char* Dwout) {
  int gid = blockIdx.x * 256 + threadIdx.x;       // 2*16*32*64 = 64K
  int lane = gid & 63, ks = (gid >> 6) & 31, vb = (gid >> 11) & 15, which = gid >> 15;
  int v = vb * 16 + (lane & 15), kb = ks * 32 + (lane >> 4) * 8;
  s16x8 vh, vl;
  #pragma unroll
  for (int i = 0; i < 8; ++i) {
    float x = which ? Wout[(kb + i) * 256 + v] : emb[v * 1024 + kb + i];
    unsigned short h = f2bf(x);
    vh[i] = (short)h;
    vl[i] = (short)f2bf(x - bf2f(h));
  }
  char* D = which ? Dwout : Demb;
  *(s16x8*)(D + (((vb * 2 + 0) * 32 + ks) << 10) + lane * 16) = vh;
  *(s16x8*)(D + (((vb * 2 + 1) * 32 + ks) << 10) + lane * 16) = vl;
}

// ---------------- prep: h0_in/h1_in [b][k] f32 -> h-frag slot0 [part2][nt2][ks32] ----
__global__ void prep_hinit(const float* __restrict__ h0, const float* __restrict__ h1,
                           char* h0s0, char* h1f) {
  int gid = blockIdx.x * 256 + threadIdx.x;       // 2*2*32*64 = 8192
  int lane = gid & 63, ks = (gid >> 6) & 31, nt = (gid >> 11) & 1, which = gid >> 12;
  const float* S = which ? h1 : h0;
  char* D = which ? h1f : h0s0;                   // slot 0 of each
  int b = nt * 16 + (lane & 15), kb = ks * 32 + (lane >> 4) * 8;
  s16x8 vh, vl;
  #pragma unroll
  for (int i = 0; i < 8; ++i) {
    float x = S[b * 1024 + kb + i];
    unsigned short h = f2bf(x);
    vh[i] = (short)h;
    vl[i] = (short)f2bf(x - bf2f(h));
  }
  *(s16x8*)(D + (((0 * 2 + nt) * 32 + ks) << 10) + lane * 16) = vh;
  *(s16x8*)(D + (((1 * 2 + nt) * 32 + ks) << 10) + lane * 16) = vl;
}

// ---------------- prep: flags = -1 (staging gate), gate-interleave b1 ----
__global__ void prep_misc(const float* __restrict__ b1, float* b1i, int* f0a, int* f1a) {
  int i = blockIdx.x * 256 + threadIdx.x;         // 4608
  if (i < 4096) b1i[i] = b1[(i & 3) * 1024 + (i >> 2)];
  if (i < 1024) { f0a[i] = -1; f1a[i] = -1; }
}

// ---------------- the persistent LSTM kernel ----------------
__global__ __launch_bounds__(256, 1) void lstm_persist(
    const int* __restrict__ tgt,
    const float* __restrict__ c0_in, const float* __restrict__ c1_in,
    const float* __restrict__ b0, const float* __restrict__ b_out,
    char* __restrict__ WA0, const char* __restrict__ WA1, const char* __restrict__ WA2,
    const char* __restrict__ WAi0, const char* __restrict__ WoutB, const char* __restrict__ embB,
    float* __restrict__ E0, const float* __restrict__ b1i,
    char* __restrict__ h0s0, char* __restrict__ h0hi, char* __restrict__ h1frag,
    int* __restrict__ f0, int* __restrict__ f1,
    float* __restrict__ out)
{
  extern __shared__ char smem[];
  // L0 layout: [0,128K) A-frags; [128K,144K) PART (16 slots); [144K,145K) RP
  // L1 layout: [0,128K) A-frags; [128K,136K) PARTc (8 slots); [136K,152K) ZPRE (2x8 slots); [152K,153K) RP
  constexpr int PART  = 131072;
  constexpr int RP0   = 131072 + 16384;
  constexpr int PARTc = 131072;
  constexpr int ZPRE  = 131072 + 8192;
  constexpr int RP1   = 131072 + 24576;
  const int tid = threadIdx.x, lane = tid & 63, wv = tid >> 6;
  const int wg = blockIdx.x;
  const bool isL0 = (wg < 128);
  const int wgl = isL0 ? wg : (wg - 128);
  const int l15 = lane & 15, l4 = lane >> 4;
  const int mi_e = wv >> 1, nt_e = wv & 1;        // epilogue role (mi, nt)

  // one-time cross-replay safety: invalidate stale L1/L2 lines
  __builtin_amdgcn_fence(__ATOMIC_ACQUIRE, "agent");

  // ---- stage A-frags into LDS: L0 = Whh0 hi+lo (sc-loads: WA0 becomes h0 slots!) ----
  if (isL0) {
    u32x4 tmp[8];
    for (int blk = 0; blk < 4; ++blk) {
      #pragma unroll
      for (int q = 0; q < 8; ++q) {
        int idx = tid + (blk * 8 + q) * 256;
        int l16 = idx & 63, ks = (idx >> 6) & 31, mi = (idx >> 11) & 1, part = idx >> 12;
        LDC(tmp[q], WA0 + ((((wgl * 2 + mi) * 2 + part) * 32 + ks) << 10) + l16 * 16);
      }
      WAITVM(0);
      #pragma unroll
      for (int q = 0; q < 8; ++q) {
        int idx = tid + (blk * 8 + q) * 256;
        int l16 = idx & 63, ks = (idx >> 6) & 31, mi = (idx >> 11) & 1, part = idx >> 12;
        *(u32x4*)(smem + (((part * 2 + mi) * 32 + ks) << 10) + l16 * 16) = tmp[q];
      }
    }
  } else {
    for (int idx = tid; idx < 8192; idx += 256) {
      int l16 = idx & 63, ks = (idx >> 6) & 31, mi = (idx >> 11) & 1, mat = idx >> 12;
      const char* W = mat ? WA2 : WA1;
      u32x4 v = *(const u32x4*)(W + ((((wgl * 2 + mi) * 2 + 0) * 32 + ks) << 10) + l16 * 16);
      *(u32x4*)(smem + (((mat * 2 + mi) * 32 + ks) << 10) + l16 * 16) = v;
    }
  }

  // ---- E0 = emb @ Wih0 + b0, own 32 gate-cols only (L0 wgs). WAi0 via sc-loads. ----
  if (isL0) {
    f32x4 C[2][4];
    #pragma unroll
    for (int a = 0; a < 2; ++a)
      #pragma unroll
      for (int b = 0; b < 4; ++b) C[a][b] = 0.0f;
    for (int ks = 0; ks < 32; ++ks) {
      s16x8 Ah0, Ah1, Al0, Al1;
      LDC(Ah0, WAi0 + ((((wgl * 2 + 0) * 2 + 0) * 32 + ks) << 10) + lane * 16);
      LDC(Ah1, WAi0 + ((((wgl * 2 + 1) * 2 + 0) * 32 + ks) << 10) + lane * 16);
      LDC(Al0, WAi0 + ((((wgl * 2 + 0) * 2 + 1) * 32 + ks) << 10) + lane * 16);
      LDC(Al1, WAi0 + ((((wgl * 2 + 1) * 2 + 1) * 32 + ks) << 10) + lane * 16);
      WAITVM(0);
      #pragma unroll
      for (int v4 = 0; v4 < 4; ++v4) {
        int vb = wv * 4 + v4;
        s16x8 Bh = ld16(embB + (((vb * 2 + 0) * 32 + ks) << 10) + lane * 16);
        s16x8 Bl = ld16(embB + (((vb * 2 + 1) * 32 + ks) << 10) + lane * 16);
        TRIPLE(C[0][v4], Ah0, Al0, Bh, Bl);
        TRIPLE(C[1][v4], Ah1, Al1, Bh, Bl);
      }
    }
    #pragma unroll
    for (int mi = 0; mi < 2; ++mi) {
      int jb4 = wgl * 32 + mi * 16 + l4 * 4;
      int u = jb4 >> 2;
      f32x4 bb;
      #pragma unroll
      for (int r = 0; r < 4; ++r) bb[r] = b0[r * 1024 + u];
      #pragma unroll
      for (int v4 = 0; v4 < 4; ++v4) {
        int v = (wv * 4 + v4) * 16 + l15;
        *(f32x4*)(E0 + v * 4096 + jb4) = C[mi][v4] + bb;
      }
    }
  }

  // ---- c state + L1 bias: one quadrant per wave ----
  float cst;
  {
    const float* cs = isL0 ? c0_in : c1_in;
    cst = cs[(nt_e * 16 + l15) * 1024 + wgl * 8 + mi_e * 4 + l4];
  }
  f32x4 b1z = {0.f, 0.f, 0.f, 0.f};
  if (!isL0) b1z = *(const f32x4*)(b1i + wgl * 32 + mi_e * 16 + (l4 << 2));

  __syncthreads();                                 // staging + E0 complete for this wg
  if (tid == 0) set_flag((isL0 ? f0 : f1) + wgl, 0);   // "staged" release (PACKED)

  // ---- sequential recurrence ----
  if (isL0) {
    for (int t = 0; t < 256; ++t) {
      const int s = t + 1;
      f32x4 C[2][2];
      #pragma unroll
      for (int a = 0; a < 2; ++a)
        #pragma unroll
        for (int b = 0; b < 2; ++b) C[a][b] = 0.0f;

      // prefetch epilogue operands (E0 static during loop; issued before poll)
      int tv = tgt[(nt_e * 16 + l15) * 256 + t];
      f32x4 e0v = *(const f32x4*)(E0 + (size_t)tv * 4096 + wgl * 32 + mi_e * 16 + (l4 << 2));
      pollP<1>(f0, lane, t);
      const char* Bb = h0slot(WA0, h0s0, h0hi, t);
      const int ksb = wv * 8;
      s16x8 P[3][4];
      #pragma unroll
      for (int d = 0; d < 2; ++d)
        #pragma unroll
        for (int q = 0; q < 4; ++q) LDP(P[d][q], Bb + ((q * 32 + ksb + d) << 10) + lane * 16);
      #pragma unroll
      for (int i = 0; i < 8; ++i) {
        const int ks = ksb + i;
        if (i < 6) {
          #pragma unroll
          for (int q = 0; q < 4; ++q) LDP(P[(i + 2) % 3][q], Bb + ((q * 32 + ks + 2) << 10) + lane * 16);
        }
        s16x8 Ah0 = ld16(smem + ((0 * 32 + ks) << 10) + lane * 16);
        s16x8 Ah1 = ld16(smem + ((1 * 32 + ks) << 10) + lane * 16);
        s16x8 Al0 = ld16(smem + ((2 * 32 + ks) << 10) + lane * 16);
        s16x8 Al1 = ld16(smem + ((3 * 32 + ks) << 10) + lane * 16);
        if (i < 6) { WAITVM(8); } else if (i == 6) { WAITVM(4); } else { WAITVM(0); }
        TRIPLE(C[0][0], Ah0, Al0, P[i % 3][0], P[i % 3][2]);
        TRIPLE(C[0][1], Ah0, Al0, P[i % 3][1], P[i % 3][3]);
        TRIPLE(C[1][0], Ah1, Al1, P[i % 3][0], P[i % 3][2]);
        TRIPLE(C[1][1], Ah1, Al1, P[i % 3][1], P[i % 3][3]);
      }

      #pragma unroll
      for (int mi = 0; mi < 2; ++mi)
        #pragma unroll
        for (int nt = 0; nt < 2; ++nt)
          *(f32x4*)(smem + PART + ((wv * 4 + mi * 2 + nt) << 10) + lane * 16) = C[mi][nt];
      __syncthreads();                             // syncA

      {
        f32x4 z = *(const f32x4*)(smem + PART + ((0 * 4 + wv) << 10) + lane * 16);
        #pragma unroll
        for (int w = 1; w < 4; ++w)
          z += *(const f32x4*)(smem + PART + ((w * 4 + wv) << 10) + lane * 16);
        z += e0v;
        float ig = 1.f / (1.f + __expf(-z[0]));
        float fg = 1.f / (1.f + __expf(-z[1]));
        float og = 1.f / (1.f + __expf(-z[3]));
        float cn = fg * cst + ig * tanhf(z[2]);
        float hn = og * tanhf(cn);
        cst = cn;
        unsigned short hb = f2bf(hn);
        unsigned short lb = f2bf(hn - bf2f(hb));
        *(short*)(smem + RP0 + ((0 + nt_e) * 16 + l15) * 16 + (mi_e * 4 + l4) * 2) = (short)hb;
        *(short*)(smem + RP0 + ((2 + nt_e) * 16 + l15) * 16 + (mi_e * 4 + l4) * 2) = (short)lb;
        if (t == 255) {
          int u = wgl * 8 + mi_e * 4 + l4, b = nt_e * 16 + l15;
          out[2097152 + b * 1024 + u] = hn;
          out[2097152 + 32768 + b * 1024 + u] = cn;
        }
      }
      __syncthreads();                             // syncB

      if (wv == 0) {
        char* hd = h0slot(WA0, h0s0, h0hi, s);
        u32x4 v = *(const u32x4*)(smem + RP0 + lane * 16);
        char* dst = hd + (((lane >> 4) * 32 + (wgl >> 2)) << 10) + ((wgl & 3) * 16 + l15) * 16;
        st16c(dst, v);
        asm volatile("s_waitcnt vmcnt(0)" ::: "memory");
        if (lane == 0) set_flag(f0 + wgl, s);
      }
    }
  } else {
    // ---- L1 prologue: zpre_0 = h0_0 @ Wih1 (slot 1) into ZPRE buf0 (waves 2,3) ----
    pollP<2>(f0, lane, 1);
    if (wv >= 2) {
      f32x4 C[2][2];
      #pragma unroll
      for (int a = 0; a < 2; ++a)
        #pragma unroll
        for (int b = 0; b < 2; ++b) C[a][b] = 0.0f;
      halfgemmT<16>(smem, WA1, h0slot(WA0, h0s0, h0hi, 1), wgl, (wv - 2) * 16, lane, C);
      #pragma unroll
      for (int mi = 0; mi < 2; ++mi)
        #pragma unroll
        for (int nt = 0; nt < 2; ++nt)
          *(f32x4*)(smem + ZPRE + ((0 * 8 + (wv - 2) * 4 + mi * 2 + nt) << 10) + lane * 16) = C[mi][nt];
    }

    for (int t = 0; t < 256; ++t) {
      const int s = t + 1;
      const int cur = t & 1;
      pollP<1>(f1, lane, t);
      if (t < 255) pollP<2>(f0, lane, t + 2);      // L0 runs ahead; usually one-shot

      if (wv < 2) {
        // CRITICAL: h1_{t-1} @ Whh1, 16 iters, ksb = wv*16
        f32x4 C[2][2];
        #pragma unroll
        for (int a = 0; a < 2; ++a)
          #pragma unroll
          for (int b = 0; b < 2; ++b) C[a][b] = 0.0f;
        halfgemmT<16>(smem + 65536, WA2, h1frag + (size_t)t * 131072, wgl, wv * 16, lane, C);
        #pragma unroll
        for (int mi = 0; mi < 2; ++mi)
          #pragma unroll
          for (int nt = 0; nt < 2; ++nt)
            *(f32x4*)(smem + PARTc + ((wv * 4 + mi * 2 + nt) << 10) + lane * 16) = C[mi][nt];
      } else {
        // PREFETCH: zpre_{t+1} = h0_{t+1} @ Wih1 (slot t+2; safe at t=255 via t=254's poll)
        f32x4 C[2][2];
        #pragma unroll
        for (int a = 0; a < 2; ++a)
          #pragma unroll
          for (int b = 0; b < 2; ++b) C[a][b] = 0.0f;
        const int sl = (t < 255) ? (t + 2) : 256;
        halfgemmT<16>(smem, WA1, h0slot(WA0, h0s0, h0hi, sl), wgl, (wv - 2) * 16, lane, C);
        #pragma unroll
        for (int mi = 0; mi < 2; ++mi)
          #pragma unroll
          for (int nt = 0; nt < 2; ++nt)
            *(f32x4*)(smem + ZPRE + (((cur ^ 1) * 8 + (wv - 2) * 4 + mi * 2 + nt) << 10) + lane * 16) = C[mi][nt];
      }
      __syncthreads();                             // syncA

      {
        f32x4 z = *(const f32x4*)(smem + PARTc + ((0 * 4 + wv) << 10) + lane * 16);
        z += *(const f32x4*)(smem + PARTc + ((1 * 4 + wv) << 10) + lane * 16);
        z += *(const f32x4*)(smem + ZPRE + ((cur * 8 + 0 * 4 + wv) << 10) + lane * 16);
        z += *(const f32x4*)(smem + ZPRE + ((cur * 8 + 1 * 4 + wv) << 10) + lane * 16);
        z += b1z;
        float ig = 1.f / (1.f + __expf(-z[0]));
        float fg = 1.f / (1.f + __expf(-z[1]));
        float og = 1.f / (1.f + __expf(-z[3]));
        float cn = fg * cst + ig * tanhf(z[2]);
        float hn = og * tanhf(cn);
        cst = cn;
        unsigned short hb = f2bf(hn);
        unsigned short lb = f2bf(hn - bf2f(hb));
        *(short*)(smem + RP1 + ((0 + nt_e) * 16 + l15) * 16 + (mi_e * 4 + l4) * 2) = (short)hb;
        *(short*)(smem + RP1 + ((2 + nt_e) * 16 + l15) * 16 + (mi_e * 4 + l4) * 2) = (short)lb;
        if (t == 255) {
          int u = wgl * 8 + mi_e * 4 + l4, b = nt_e * 16 + l15;
          out[2097152 + 65536 + b * 1024 + u] = hn;
          out[2097152 + 65536 + 32768 + b * 1024 + u] = cn;
        }
      }
      __syncthreads();                             // syncB

      if (wv == 0) {
        char* hd = h1frag + (size_t)s * 131072;
        u32x4 v = *(const u32x4*)(smem + RP1 + lane * 16);
        char* dst = hd + (((lane >> 4) * 32 + (wgl >> 2)) << 10) + ((wgl & 3) * 16 + l15) * 16;
        st16c(dst, v);
        asm volatile("s_waitcnt vmcnt(0)" ::: "memory");
        if (lane == 0) set_flag(f1 + wgl, s);
      }
    }
  }

  // ---- projection: logits[b][t][v] = h1_t @ W_out + b_out ; one t per CU ----
  // L0 wgs (finish first) take EARLY t (flags long set); L1 wgs take late t.
  {
    const int tp = isL0 ? wgl : (128 + wgl);
    pollP<32>(f1, lane, tp + 1);
    const char* A = h1frag + (size_t)(tp + 1) * 131072;
    f32x4 C[2][4];
    #pragma unroll
    for (int a = 0; a < 2; ++a)
      #pragma unroll
      for (int b = 0; b < 4; ++b) C[a][b] = 0.0f;
    s16x8 QA[4], QB[4];
    #pragma unroll
    for (int q = 0; q < 4; ++q) LDP(QA[q], A + ((q * 32 + 0) << 10) + lane * 16);
    for (int kk = 0; kk < 16; ++kk) {
      const int ks = kk * 2;
      #pragma unroll
      for (int q = 0; q < 4; ++q) LDP(QB[q], A + ((q * 32 + ks + 1) << 10) + lane * 16);
      asm volatile("s_waitcnt vmcnt(4)" ::: "memory");
      __builtin_amdgcn_sched_barrier(0);
      #pragma unroll
      for (int v4 = 0; v4 < 4; ++v4) {
        int vb = wv * 4 + v4;
        s16x8 Bh = ld16(WoutB + (((vb * 2 + 0) * 32 + ks) << 10) + lane * 16);
        s16x8 Bl = ld16(WoutB + (((vb * 2 + 1) * 32 + ks) << 10) + lane * 16);
        C[0][v4] = MF(QA[0], Bh, C[0][v4]); C[0][v4] = MF(QA[0], Bl, C[0][v4]); C[0][v4] = MF(QA[2], Bh, C[0][v4]);
        C[1][v4] = MF(QA[1], Bh, C[1][v4]); C[1][v4] = MF(QA[1], Bl, C[1][v4]); C[1][v4] = MF(QA[3], Bh, C[1][v4]);
      }
      if (kk < 15) {
        #pragma unroll
        for (int q = 0; q < 4; ++q) LDP(QA[q], A + ((q * 32 + ks + 2) << 10) + lane * 16);
        asm volatile("s_waitcnt vmcnt(4)" ::: "memory");
      } else {
        asm volatile("s_waitcnt vmcnt(0)" ::: "memory");
      }
      __builtin_amdgcn_sched_barrier(0);
      #pragma unroll
      for (int v4 = 0; v4 < 4; ++v4) {
        int vb = wv * 4 + v4;
        s16x8 Bh = ld16(WoutB + (((vb * 2 + 0) * 32 + ks + 1) << 10) + lane * 16);
        s16x8 Bl = ld16(WoutB + (((vb * 2 + 1) * 32 + ks + 1) << 10) + lane * 16);
        C[0][v4] = MF(QB[0], Bh, C[0][v4]); C[0][v4] = MF(QB[0], Bl, C[0][v4]); C[0][v4] = MF(QB[2], Bh, C[0][v4]);
        C[1][v4] = MF(QB[1], Bh, C[1][v4]); C[1][v4] = MF(QB[1], Bl, C[1][v4]); C[1][v4] = MF(QB[3], Bh, C[1][v4]);
      }
    }
    #pragma unroll
    for (int nt = 0; nt < 2; ++nt)
      #pragma unroll
      for (int v4 = 0; v4 < 4; ++v4) {
        int v = (wv * 4 + v4) * 16 + l15;
        float bo = b_out[v];
        #pragma unroll
        for (int r = 0; r < 4; ++r) {
          int b = nt * 16 + l4 * 4 + r;
          out[((size_t)b * 256 + tp) * 256 + v] = C[nt][v4][r] + bo;
        }
      }
  }
}

extern "C" void kernel_launch(void* const* d_in, const int* in_sizes, int n_in,
                              void* d_out, int out_size, void* d_ws, size_t ws_size,
                              hipStream_t stream) {
  const int*   targets = (const int*)d_in[1];
  const float* h0_in   = (const float*)d_in[2];
  const float* c0_in   = (const float*)d_in[3];
  const float* h1_in   = (const float*)d_in[4];
  const float* c1_in   = (const float*)d_in[5];
  const float* emb     = (const float*)d_in[6];
  const float* W_ih0   = (const float*)d_in[7];
  const float* W_hh0   = (const float*)d_in[8];
  const float* b0      = (const float*)d_in[9];
  const float* W_ih1   = (const float*)d_in[10];
  const float* W_hh1   = (const float*)d_in[11];
  const float* b1      = (const float*)d_in[12];
  const float* W_out   = (const float*)d_in[13];
  const float* b_out   = (const float*)d_in[14];
  float* out = (float*)d_out;

  char* ws = (char*)d_ws;
  char*  WA0    = ws;                         // Whh0 A-frags hi/lo 16MB; becomes h0 slots 1..128
  char*  WA1    = ws + 16777216;              // Wih1 (hi staged, lo streamed)
  char*  WA2    = ws + 33554432;              // Whh1
  char*  WoutB  = ws + 50331648;              // W_out B-frags, 1MB
  char*  embB   = ws + 51380224;              // emb B-frags, 1MB
  float* E0     = (float*)(ws + 52428800);    // 4MB f32
  float* b1i    = (float*)(ws + 56623104);    // 16KB
  int*   f0     = (int*)(ws + 56639488);      // PACKED flag array (128 ints)
  int*   f1     = (int*)(ws + 56643584);      // PACKED flag array (128 ints)
  char*  h0s0   = ws + 56647680;              // h0 slot 0, 128KB
  char*  h0hi   = ws + 56778752;              // h0 slots 129..256, 16MB
  char*  h1frag = ws + 73555968;              // 257 slots x 128KB (~33.7MB) -> end ~102.3MB
  char*  WAi0   = h1frag + 16777216;          // Wih0 A-frags alias h1 slots 128..255
                                              // (read via sc-loads at E0; slot 128 written step 127)

  prep_misc <<<18,   256, 0, stream>>>(b1, b1i, f0, f1);
  prep_wfrag<<<8192, 256, 0, stream>>>(W_hh0, W_ih1, W_hh1, W_ih0, WA0, WA1, WA2, WAi0);
  prep_bfrag<<<256,  256, 0, stream>>>(emb, W_out, embB, WoutB);
  prep_hinit<<<32,   256, 0, stream>>>(h0_in, h1_in, h0s0, h1frag);

  hipFuncSetAttribute(reinterpret_cast<const void*>(lstm_persist),
                      hipFuncAttributeMaxDynamicSharedMemorySize, 156672);
  lstm_persist<<<256, 256, 156672, stream>>>(
      targets, c0_in, c1_in, b0, b_out,
      WA0, WA1, WA2, WAi0, WoutB, embB,
      E0, b1i, h0s0, h0hi, h1frag, f0, f1, out);
}

// Round 9
// 2607.006 us; speedup vs baseline: 1.2402x; 1.2402x over previous
//
#include <hip/hip_runtime.h>
#include <cstdint>

// CharRNN 2-layer LSTM, B=32,T=256,H=1024,V=256. Persistent kernel, round 9:
//   Topology = round 7 (best): wgs 0..127 L0 chain; wgs 128..255 L1 chain with
//   critical h1@Whh1 on ALL 4 waves (8 iters each) and h0@Wih1 prefetched one step
//   ahead AFTER the flag (off the consumer path). NEW: all-up-front load issue —
//   each GEMM issues its full B/W-lo load stream (32 or 48 loads) before computing,
//   draining vmcnt with literal per-iteration waits. Kills the per-iteration L3 stall.
//   Flags PACKED (4B stride). h slots write-once; h0 slots 1..128 alias WA0.
//   math: mfma_f32_16x16x32_bf16 split-bf16 (hi*hi + hi*lo + lo*hi) ~ f32 accuracy.

typedef float    f32x4 __attribute__((ext_vector_type(4)));
typedef short    s16x8 __attribute__((ext_vector_type(8)));
typedef unsigned u32x4 __attribute__((ext_vector_type(4)));

#define DEV __device__ __forceinline__

DEV unsigned short f2bf(float x){
  unsigned u = __builtin_bit_cast(unsigned, x);
  unsigned r = (u + 0x7fffu + ((u >> 16) & 1u)) >> 16;   // round-nearest-even
  return (unsigned short)r;
}
DEV float bf2f(unsigned short b){ return __builtin_bit_cast(float, ((unsigned)b) << 16); }

DEV s16x8 ld16(const void* p){ return *(const s16x8*)p; }

DEV f32x4 MF(s16x8 a, s16x8 b, f32x4 c){
  return __builtin_amdgcn_mfma_f32_16x16x32_bf16(a, b, c, 0, 0, 0);
}

// coherent (bypass L1/L2) 16B load — only for WA0/WAi0 (aliased regions)
#define LDC(dst, ptr)  asm volatile("global_load_dwordx4 %0, %1, off sc0 sc1" : "=v"(dst) : "v"(ptr))
// plain cached 16B load (participates in our vmcnt accounting)
#define LDP(dst, ptr)  asm volatile("global_load_dwordx4 %0, %1, off"         : "=v"(dst) : "v"(ptr))
#define WAITVM(n) do { asm volatile("s_waitcnt vmcnt(" #n ")" ::: "memory"); \
                       __builtin_amdgcn_sched_barrier(0); } while (0)
#define CFENCE()  asm volatile("" ::: "memory")
#define TRIPLE(Cmn, Ahm, Alm, Bhn, Bln) do { \
    Cmn = MF(Ahm, Bhn, Cmn); Cmn = MF(Ahm, Bln, Cmn); Cmn = MF(Alm, Bhn, Cmn); } while (0)

// literal vmcnt wait via builtin (vmcnt=N, expcnt/lgkmcnt unmasked)
template<int N> DEV void waitvm(){
  __builtin_amdgcn_s_waitcnt((N & 15) | (7 << 4) | (15 << 8) | ((N >> 4) << 14));
  __builtin_amdgcn_sched_barrier(0);
}

DEV void st16c(void* p, u32x4 v){   // coherent 16B store (write-through)
  asm volatile("global_store_dwordx4 %0, %1, off sc0 sc1" :: "v"(p), "v"(v) : "memory");
}
DEV void set_flag(int* p, int v){
  __hip_atomic_store(p, v, __ATOMIC_RELAXED, __HIP_MEMORY_SCOPE_AGENT);
}
// collective poll over PACKED flags (128 ints contiguous). 8 cache lines per iteration.
template<int SLP>
DEV void pollP(const int* f, int lane, int target){
  const int* p0 = f + lane;
  const int* p1 = f + 64 + lane;
  for (;;) {
    int a = __hip_atomic_load(p0, __ATOMIC_RELAXED, __HIP_MEMORY_SCOPE_AGENT);
    int b = __hip_atomic_load(p1, __ATOMIC_RELAXED, __HIP_MEMORY_SCOPE_AGENT);
    if (__all((a >= target) && (b >= target))) break;
    __builtin_amdgcn_s_sleep(SLP);
  }
  CFENCE();
}
// h0 slot address: 0 -> s0 buf; 1..128 -> aliased over WA0; 129..256 -> hi buf
DEV char* h0slot(char* wa0, char* s0, char* hi, int s){
  return (s == 0) ? s0 : ((s <= 128) ? wa0 + ((size_t)(s - 1) << 17)
                                     : hi  + ((size_t)(s - 129) << 17));
}

// all-up-front L1-style half-GEMM: A hi from LDS, A lo streamed, 48 loads then drain
DEV void gemm6(const char* smemMat, const char* ALb, const char* Bb,
               int wgl, int ksb, int lane, f32x4 (&C)[2][2]) {
  s16x8 P[8][4], AL[8][2];
  #pragma unroll
  for (int d = 0; d < 8; ++d) {
    #pragma unroll
    for (int q = 0; q < 4; ++q) LDP(P[d][q], Bb + ((q * 32 + ksb + d) << 10) + lane * 16);
    LDP(AL[d][0], ALb + ((((wgl * 2 + 0) * 2 + 1) * 32 + ksb + d) << 10) + lane * 16);
    LDP(AL[d][1], ALb + ((((wgl * 2 + 1) * 2 + 1) * 32 + ksb + d) << 10) + lane * 16);
  }
#define G6IT(i, W) { const int ks = ksb + i; \
    s16x8 Ah0 = ld16(smemMat + ((0 * 32 + ks) << 10) + lane * 16); \
    s16x8 Ah1 = ld16(smemMat + ((1 * 32 + ks) << 10) + lane * 16); \
    waitvm<W>(); \
    TRIPLE(C[0][0], Ah0, AL[i][0], P[i][0], P[i][2]); \
    TRIPLE(C[0][1], Ah0, AL[i][0], P[i][1], P[i][3]); \
    TRIPLE(C[1][0], Ah1, AL[i][1], P[i][0], P[i][2]); \
    TRIPLE(C[1][1], Ah1, AL[i][1], P[i][1], P[i][3]); }
  G6IT(0, 42) G6IT(1, 36) G6IT(2, 30) G6IT(3, 24)
  G6IT(4, 18) G6IT(5, 12) G6IT(6, 6)  G6IT(7, 0)
#undef G6IT
}

// ---------------- prep: W[k][g*H+u] -> A-frag hi/lo bf16 [jb256][part2][ks32][64*16B] ----
__global__ void prep_wfrag(const float* __restrict__ W0, const float* __restrict__ W1,
                           const float* __restrict__ W2, const float* __restrict__ W3,
                           char* D0, char* D1, char* D2, char* D3) {
  int gid = blockIdx.x * 256 + threadIdx.x;       // 4*256*32*64 = 2M
  int lane = gid & 63, ks = (gid >> 6) & 31, jb = (gid >> 11) & 255, mat = gid >> 19;
  const float* S = (mat == 0) ? W0 : (mat == 1) ? W1 : (mat == 2) ? W2 : W3;
  char* D = (mat == 0) ? D0 : (mat == 1) ? D1 : (mat == 2) ? D2 : D3;
  int jp = jb * 16 + (lane & 15), u = jp >> 2, g = jp & 3;
  int kb = ks * 32 + (lane >> 4) * 8;
  s16x8 vh, vl;
  #pragma unroll
  for (int i = 0; i < 8; ++i) {
    float x = S[(kb + i) * 4096 + g * 1024 + u];
    unsigned short h = f2bf(x);
    vh[i] = (short)h;
    vl[i] = (short)f2bf(x - bf2f(h));
  }
  *(s16x8*)(D + (((jb * 2 + 0) * 32 + ks) << 10) + lane * 16) = vh;
  *(s16x8*)(D + (((jb * 2 + 1) * 32 + ks) << 10) + lane * 16) = vl;
}

// ---------------- prep: emb [v][k] and W_out [k][v] -> B-frag hi/lo [vb16][part2][ks32] ----
__global__ void prep_bfrag(const float* __restrict__ emb, const float* __restrict__ Wout,
                           char* Demb, char* Dwout) {
  int gid = blockIdx.x * 256 + threadIdx.x;       // 2*16*32*64 = 64K
  int lane = gid & 63, ks = (gid >> 6) & 31, vb = (gid >> 11) & 15, which = gid >> 15;
  int v = vb * 16 + (lane & 15), kb = ks * 32 + (lane >> 4) * 8;
  s16x8 vh, vl;
  #pragma unroll
  for (int i = 0; i < 8; ++i) {
    float x = which ? Wout[(kb + i) * 256 + v] : emb[v * 1024 + kb + i];
    unsigned short h = f2bf(x);
    vh[i] = (short)h;
    vl[i] = (short)f2bf(x - bf2f(h));
  }
  char* D = which ? Dwout : Demb;
  *(s16x8*)(D + (((vb * 2 + 0) * 32 + ks) << 10) + lane * 16) = vh;
  *(s16x8*)(D + (((vb * 2 + 1) * 32 + ks) << 10) + lane * 16) = vl;
}

// ---------------- prep: h0_in/h1_in [b][k] f32 -> h-frag slot0 [part2][nt2][ks32] ----
__global__ void prep_hinit(const float* __restrict__ h0, const float* __restrict__ h1,
                           char* h0s0, char* h1f) {
  int gid = blockIdx.x * 256 + threadIdx.x;       // 2*2*32*64 = 8192
  int lane = gid & 63, ks = (gid >> 6) & 31, nt = (gid >> 11) & 1, which = gid >> 12;
  const float* S = which ? h1 : h0;
  char* D = which ? h1f : h0s0;                   // slot 0 of each
  int b = nt * 16 + (lane & 15), kb = ks * 32 + (lane >> 4) * 8;
  s16x8 vh, vl;
  #pragma unroll
  for (int i = 0; i < 8; ++i) {
    float x = S[b * 1024 + kb + i];
    unsigned short h = f2bf(x);
    vh[i] = (short)h;
    vl[i] = (short)f2bf(x - bf2f(h));
  }
  *(s16x8*)(D + (((0 * 2 + nt) * 32 + ks) << 10) + lane * 16) = vh;
  *(s16x8*)(D + (((1 * 2 + nt) * 32 + ks) << 10) + lane * 16) = vl;
}

// ---------------- prep: flags = -1 (staging gate), gate-interleave b1 ----
__global__ void prep_misc(const float* __restrict__ b1, float* b1i, int* f0a, int* f1a) {
  int i = blockIdx.x * 256 + threadIdx.x;         // 4608
  if (i < 4096) b1i[i] = b1[(i & 3) * 1024 + (i >> 2)];
  if (i < 1024) { f0a[i] = -1; f1a[i] = -1; }
}

// ---------------- the persistent LSTM kernel ----------------
__global__ __launch_bounds__(256, 1) void lstm_persist(
    const int* __restrict__ tgt,
    const float* __restrict__ c0_in, const float* __restrict__ c1_in,
    const float* __restrict__ b0, const float* __restrict__ b_out,
    char* __restrict__ WA0, const char* __restrict__ WA1, const char* __restrict__ WA2,
    const char* __restrict__ WAi0, const char* __restrict__ WoutB, const char* __restrict__ embB,
    float* __restrict__ E0, const float* __restrict__ b1i,
    char* __restrict__ h0s0, char* __restrict__ h0hi, char* __restrict__ h1frag,
    int* __restrict__ f0, int* __restrict__ f1,
    float* __restrict__ out)
{
  extern __shared__ char smem[];     // 128KB A-frags + 16KB partials + 1KB repack
  constexpr int PART = 131072;
  constexpr int RP   = 131072 + 16384;
  const int tid = threadIdx.x, lane = tid & 63, wv = tid >> 6;
  const int wg = blockIdx.x;
  const bool isL0 = (wg < 128);
  const int wgl = isL0 ? wg : (wg - 128);
  const int l15 = lane & 15, l4 = lane >> 4;
  const int mi_e = wv >> 1, nt_e = wv & 1;        // epilogue role (mi, nt)

  // one-time cross-replay safety: invalidate stale L1/L2 lines
  __builtin_amdgcn_fence(__ATOMIC_ACQUIRE, "agent");

  // ---- stage A-frags into LDS: L0 = Whh0 hi+lo (sc-loads: WA0 becomes h0 slots!) ----
  if (isL0) {
    u32x4 tmp[8];
    for (int blk = 0; blk < 4; ++blk) {
      #pragma unroll
      for (int q = 0; q < 8; ++q) {
        int idx = tid + (blk * 8 + q) * 256;
        int l16 = idx & 63, ks = (idx >> 6) & 31, mi = (idx >> 11) & 1, part = idx >> 12;
        LDC(tmp[q], WA0 + ((((wgl * 2 + mi) * 2 + part) * 32 + ks) << 10) + l16 * 16);
      }
      WAITVM(0);
      #pragma unroll
      for (int q = 0; q < 8; ++q) {
        int idx = tid + (blk * 8 + q) * 256;
        int l16 = idx & 63, ks = (idx >> 6) & 31, mi = (idx >> 11) & 1, part = idx >> 12;
        *(u32x4*)(smem + (((part * 2 + mi) * 32 + ks) << 10) + l16 * 16) = tmp[q];
      }
    }
  } else {
    for (int idx = tid; idx < 8192; idx += 256) {
      int l16 = idx & 63, ks = (idx >> 6) & 31, mi = (idx >> 11) & 1, mat = idx >> 12;
      const char* W = mat ? WA2 : WA1;
      u32x4 v = *(const u32x4*)(W + ((((wgl * 2 + mi) * 2 + 0) * 32 + ks) << 10) + l16 * 16);
      *(u32x4*)(smem + (((mat * 2 + mi) * 32 + ks) << 10) + l16 * 16) = v;
    }
  }

  // ---- E0 = emb @ Wih0 + b0, own 32 gate-cols only (L0 wgs). WAi0 via sc-loads. ----
  if (isL0) {
    f32x4 C[2][4];
    #pragma unroll
    for (int a = 0; a < 2; ++a)
      #pragma unroll
      for (int b = 0; b < 4; ++b) C[a][b] = 0.0f;
    for (int ks = 0; ks < 32; ++ks) {
      s16x8 Ah0, Ah1, Al0, Al1;
      LDC(Ah0, WAi0 + ((((wgl * 2 + 0) * 2 + 0) * 32 + ks) << 10) + lane * 16);
      LDC(Ah1, WAi0 + ((((wgl * 2 + 1) * 2 + 0) * 32 + ks) << 10) + lane * 16);
      LDC(Al0, WAi0 + ((((wgl * 2 + 0) * 2 + 1) * 32 + ks) << 10) + lane * 16);
      LDC(Al1, WAi0 + ((((wgl * 2 + 1) * 2 + 1) * 32 + ks) << 10) + lane * 16);
      WAITVM(0);
      #pragma unroll
      for (int v4 = 0; v4 < 4; ++v4) {
        int vb = wv * 4 + v4;
        s16x8 Bh = ld16(embB + (((vb * 2 + 0) * 32 + ks) << 10) + lane * 16);
        s16x8 Bl = ld16(embB + (((vb * 2 + 1) * 32 + ks) << 10) + lane * 16);
        TRIPLE(C[0][v4], Ah0, Al0, Bh, Bl);
        TRIPLE(C[1][v4], Ah1, Al1, Bh, Bl);
      }
    }
    #pragma unroll
    for (int mi = 0; mi < 2; ++mi) {
      int jb4 = wgl * 32 + mi * 16 + l4 * 4;
      int u = jb4 >> 2;
      f32x4 bb;
      #pragma unroll
      for (int r = 0; r < 4; ++r) bb[r] = b0[r * 1024 + u];
      #pragma unroll
      for (int v4 = 0; v4 < 4; ++v4) {
        int v = (wv * 4 + v4) * 16 + l15;
        *(f32x4*)(E0 + v * 4096 + jb4) = C[mi][v4] + bb;
      }
    }
  }

  // ---- c state + L1 bias: one quadrant per wave ----
  float cst;
  {
    const float* cs = isL0 ? c0_in : c1_in;
    cst = cs[(nt_e * 16 + l15) * 1024 + wgl * 8 + mi_e * 4 + l4];
  }
  f32x4 b1z = {0.f, 0.f, 0.f, 0.f};
  if (!isL0) b1z = *(const f32x4*)(b1i + wgl * 32 + mi_e * 16 + (l4 << 2));

  __syncthreads();                                 // staging + E0 complete for this wg
  if (tid == 0) set_flag((isL0 ? f0 : f1) + wgl, 0);   // "staged" release (PACKED)

  // ---- sequential recurrence ----
  if (isL0) {
    for (int t = 0; t < 256; ++t) {
      const int s = t + 1;
      f32x4 C[2][2];
      #pragma unroll
      for (int a = 0; a < 2; ++a)
        #pragma unroll
        for (int b = 0; b < 2; ++b) C[a][b] = 0.0f;

      // prefetch epilogue operands (E0 static during loop; issued before poll)
      int tv = tgt[(nt_e * 16 + l15) * 256 + t];
      f32x4 e0v = *(const f32x4*)(E0 + (size_t)tv * 4096 + wgl * 32 + mi_e * 16 + (l4 << 2));
      pollP<1>(f0, lane, t);
      const char* Bb = h0slot(WA0, h0s0, h0hi, t);
      const int ksb = wv * 8;
      // all-up-front: 32 loads, then drain with literal waits
      s16x8 P[8][4];
      #pragma unroll
      for (int d = 0; d < 8; ++d)
        #pragma unroll
        for (int q = 0; q < 4; ++q) LDP(P[d][q], Bb + ((q * 32 + ksb + d) << 10) + lane * 16);
#define L0IT(i, W) { const int ks = ksb + i; \
      s16x8 Ah0 = ld16(smem + ((0 * 32 + ks) << 10) + lane * 16); \
      s16x8 Ah1 = ld16(smem + ((1 * 32 + ks) << 10) + lane * 16); \
      s16x8 Al0 = ld16(smem + ((2 * 32 + ks) << 10) + lane * 16); \
      s16x8 Al1 = ld16(smem + ((3 * 32 + ks) << 10) + lane * 16); \
      waitvm<W>(); \
      TRIPLE(C[0][0], Ah0, Al0, P[i][0], P[i][2]); \
      TRIPLE(C[0][1], Ah0, Al0, P[i][1], P[i][3]); \
      TRIPLE(C[1][0], Ah1, Al1, P[i][0], P[i][2]); \
      TRIPLE(C[1][1], Ah1, Al1, P[i][1], P[i][3]); }
      L0IT(0, 28) L0IT(1, 24) L0IT(2, 20) L0IT(3, 16)
      L0IT(4, 12) L0IT(5, 8)  L0IT(6, 4)  L0IT(7, 0)
#undef L0IT

      #pragma unroll
      for (int mi = 0; mi < 2; ++mi)
        #pragma unroll
        for (int nt = 0; nt < 2; ++nt)
          *(f32x4*)(smem + PART + ((wv * 4 + mi * 2 + nt) << 10) + lane * 16) = C[mi][nt];
      __syncthreads();                             // syncA

      {
        f32x4 z = *(const f32x4*)(smem + PART + ((0 * 4 + wv) << 10) + lane * 16);
        #pragma unroll
        for (int w = 1; w < 4; ++w)
          z += *(const f32x4*)(smem + PART + ((w * 4 + wv) << 10) + lane * 16);
        z += e0v;
        float ig = 1.f / (1.f + __expf(-z[0]));
        float fg = 1.f / (1.f + __expf(-z[1]));
        float og = 1.f / (1.f + __expf(-z[3]));
        float cn = fg * cst + ig * tanhf(z[2]);
        float hn = og * tanhf(cn);
        cst = cn;
        unsigned short hb = f2bf(hn);
        unsigned short lb = f2bf(hn - bf2f(hb));
        *(short*)(smem + RP + ((0 + nt_e) * 16 + l15) * 16 + (mi_e * 4 + l4) * 2) = (short)hb;
        *(short*)(smem + RP + ((2 + nt_e) * 16 + l15) * 16 + (mi_e * 4 + l4) * 2) = (short)lb;
        if (t == 255) {
          int u = wgl * 8 + mi_e * 4 + l4, b = nt_e * 16 + l15;
          out[2097152 + b * 1024 + u] = hn;
          out[2097152 + 32768 + b * 1024 + u] = cn;
        }
      }
      __syncthreads();                             // syncB

      if (wv == 0) {
        char* hd = h0slot(WA0, h0s0, h0hi, s);
        u32x4 v = *(const u32x4*)(smem + RP + lane * 16);
        char* dst = hd + (((lane >> 4) * 32 + (wgl >> 2)) << 10) + ((wgl & 3) * 16 + l15) * 16;
        st16c(dst, v);
        asm volatile("s_waitcnt vmcnt(0)" ::: "memory");
        if (lane == 0) set_flag(f0 + wgl, s);
      }
    }
  } else {
    // ---- L1 prologue: zpre_0 = h0_1-slot @ Wih1 on all 4 waves ----
    f32x4 zpre;
    {
      pollP<2>(f0, lane, 1);
      f32x4 C2[2][2];
      #pragma unroll
      for (int a = 0; a < 2; ++a)
        #pragma unroll
        for (int b = 0; b < 2; ++b) C2[a][b] = 0.0f;
      gemm6(smem, WA1, h0slot(WA0, h0s0, h0hi, 1), wgl, wv * 8, lane, C2);
      #pragma unroll
      for (int mi = 0; mi < 2; ++mi)
        #pragma unroll
        for (int nt = 0; nt < 2; ++nt)
          *(f32x4*)(smem + PART + ((wv * 4 + mi * 2 + nt) << 10) + lane * 16) = C2[mi][nt];
      __syncthreads();                             // syncC
      zpre = *(const f32x4*)(smem + PART + ((0 * 4 + wv) << 10) + lane * 16);
      #pragma unroll
      for (int w = 1; w < 4; ++w)
        zpre += *(const f32x4*)(smem + PART + ((w * 4 + wv) << 10) + lane * 16);
      __syncthreads();                             // syncD
    }

    for (int t = 0; t < 256; ++t) {
      const int s = t + 1;
      f32x4 C[2][2];
      #pragma unroll
      for (int a = 0; a < 2; ++a)
        #pragma unroll
        for (int b = 0; b < 2; ++b) C[a][b] = 0.0f;

      // ---- CRITICAL: h1_{t-1} @ Whh1 on all 4 waves (all-up-front) ----
      pollP<1>(f1, lane, t);
      gemm6(smem + 65536, WA2, h1frag + (size_t)t * 131072, wgl, wv * 8, lane, C);

      #pragma unroll
      for (int mi = 0; mi < 2; ++mi)
        #pragma unroll
        for (int nt = 0; nt < 2; ++nt)
          *(f32x4*)(smem + PART + ((wv * 4 + mi * 2 + nt) << 10) + lane * 16) = C[mi][nt];
      __syncthreads();                             // syncA

      {
        f32x4 z = *(const f32x4*)(smem + PART + ((0 * 4 + wv) << 10) + lane * 16);
        #pragma unroll
        for (int w = 1; w < 4; ++w)
          z += *(const f32x4*)(smem + PART + ((w * 4 + wv) << 10) + lane * 16);
        z += zpre + b1z;
        float ig = 1.f / (1.f + __expf(-z[0]));
        float fg = 1.f / (1.f + __expf(-z[1]));
        float og = 1.f / (1.f + __expf(-z[3]));
        float cn = fg * cst + ig * tanhf(z[2]);
        float hn = og * tanhf(cn);
        cst = cn;
        unsigned short hb = f2bf(hn);
        unsigned short lb = f2bf(hn - bf2f(hb));
        *(short*)(smem + RP + ((0 + nt_e) * 16 + l15) * 16 + (mi_e * 4 + l4) * 2) = (short)hb;
        *(short*)(smem + RP + ((2 + nt_e) * 16 + l15) * 16 + (mi_e * 4 + l4) * 2) = (short)lb;
        if (t == 255) {
          int u = wgl * 8 + mi_e * 4 + l4, b = nt_e * 16 + l15;
          out[2097152 + 65536 + b * 1024 + u] = hn;
          out[2097152 + 65536 + 32768 + b * 1024 + u] = cn;
        }
      }
      __syncthreads();                             // syncB

      if (wv == 0) {
        char* hd = h1frag + (size_t)s * 131072;
        u32x4 v = *(const u32x4*)(smem + RP + lane * 16);
        char* dst = hd + (((lane >> 4) * 32 + (wgl >> 2)) << 10) + ((wgl & 3) * 16 + l15) * 16;
        st16c(dst, v);
        asm volatile("s_waitcnt vmcnt(0)" ::: "memory");
        if (lane == 0) set_flag(f1 + wgl, s);
      }

      // ---- off-critical: zpre_{t+1} = h0_{t+1} @ Wih1 (slot t+2), after flag ----
      if (t < 255) {
        pollP<2>(f0, lane, t + 2);
        f32x4 C2[2][2];
        #pragma unroll
        for (int a = 0; a < 2; ++a)
          #pragma unroll
          for (int b = 0; b < 2; ++b) C2[a][b] = 0.0f;
        gemm6(smem, WA1, h0slot(WA0, h0s0, h0hi, t + 2), wgl, wv * 8, lane, C2);
        #pragma unroll
        for (int mi = 0; mi < 2; ++mi)
          #pragma unroll
          for (int nt = 0; nt < 2; ++nt)
            *(f32x4*)(smem + PART + ((wv * 4 + mi * 2 + nt) << 10) + lane * 16) = C2[mi][nt];
        __syncthreads();                           // syncC
        zpre = *(const f32x4*)(smem + PART + ((0 * 4 + wv) << 10) + lane * 16);
        #pragma unroll
        for (int w = 1; w < 4; ++w)
          zpre += *(const f32x4*)(smem + PART + ((w * 4 + wv) << 10) + lane * 16);
        __syncthreads();                           // syncD
      }
    }
  }

  // ---- projection: logits[b][t][v] = h1_t @ W_out + b_out ; one t per CU ----
  // L0 wgs (finish first) take EARLY t (flags long set); L1 wgs take late t.
  {
    const int tp = isL0 ? wgl : (128 + wgl);
    pollP<32>(f1, lane, tp + 1);
    const char* A = h1frag + (size_t)(tp + 1) * 131072;
    f32x4 C[2][4];
    #pragma unroll
    for (int a = 0; a < 2; ++a)
      #pragma unroll
      for (int b = 0; b < 4; ++b) C[a][b] = 0.0f;
    s16x8 QA[4], QB[4];
    #pragma unroll
    for (int q = 0; q < 4; ++q) LDP(QA[q], A + ((q * 32 + 0) << 10) + lane * 16);
    for (int kk = 0; kk < 16; ++kk) {
      const int ks = kk * 2;
      #pragma unroll
      for (int q = 0; q < 4; ++q) LDP(QB[q], A + ((q * 32 + ks + 1) << 10) + lane * 16);
      asm volatile("s_waitcnt vmcnt(4)" ::: "memory");
      __builtin_amdgcn_sched_barrier(0);
      #pragma unroll
      for (int v4 = 0; v4 < 4; ++v4) {
        int vb = wv * 4 + v4;
        s16x8 Bh = ld16(WoutB + (((vb * 2 + 0) * 32 + ks) << 10) + lane * 16);
        s16x8 Bl = ld16(WoutB + (((vb * 2 + 1) * 32 + ks) << 10) + lane * 16);
        C[0][v4] = MF(QA[0], Bh, C[0][v4]); C[0][v4] = MF(QA[0], Bl, C[0][v4]); C[0][v4] = MF(QA[2], Bh, C[0][v4]);
        C[1][v4] = MF(QA[1], Bh, C[1][v4]); C[1][v4] = MF(QA[1], Bl, C[1][v4]); C[1][v4] = MF(QA[3], Bh, C[1][v4]);
      }
      if (kk < 15) {
        #pragma unroll
        for (int q = 0; q < 4; ++q) LDP(QA[q], A + ((q * 32 + ks + 2) << 10) + lane * 16);
        asm volatile("s_waitcnt vmcnt(4)" ::: "memory");
      } else {
        asm volatile("s_waitcnt vmcnt(0)" ::: "memory");
      }
      __builtin_amdgcn_sched_barrier(0);
      #pragma unroll
      for (int v4 = 0; v4 < 4; ++v4) {
        int vb = wv * 4 + v4;
        s16x8 Bh = ld16(WoutB + (((vb * 2 + 0) * 32 + ks + 1) << 10) + lane * 16);
        s16x8 Bl = ld16(WoutB + (((vb * 2 + 1) * 32 + ks + 1) << 10) + lane * 16);
        C[0][v4] = MF(QB[0], Bh, C[0][v4]); C[0][v4] = MF(QB[0], Bl, C[0][v4]); C[0][v4] = MF(QB[2], Bh, C[0][v4]);
        C[1][v4] = MF(QB[1], Bh, C[1][v4]); C[1][v4] = MF(QB[1], Bl, C[1][v4]); C[1][v4] = MF(QB[3], Bh, C[1][v4]);
      }
    }
    #pragma unroll
    for (int nt = 0; nt < 2; ++nt)
      #pragma unroll
      for (int v4 = 0; v4 < 4; ++v4) {
        int v = (wv * 4 + v4) * 16 + l15;
        float bo = b_out[v];
        #pragma unroll
        for (int r = 0; r < 4; ++r) {
          int b = nt * 16 + l4 * 4 + r;
          out[((size_t)b * 256 + tp) * 256 + v] = C[nt][v4][r] + bo;
        }
      }
  }
}

extern "C" void kernel_launch(void* const* d_in, const int* in_sizes, int n_in,
                              void* d_out, int out_size, void* d_ws, size_t ws_size,
                              hipStream_t stream) {
  const int*   targets = (const int*)d_in[1];
  const float* h0_in   = (const float*)d_in[2];
  const float* c0_in   = (const float*)d_in[3];
  const float* h1_in   = (const float*)d_in[4];
  const float* c1_in   = (const float*)d_in[5];
  const float* emb     = (const float*)d_in[6];
  const float* W_ih0   = (const float*)d_in[7];
  const float* W_hh0   = (const float*)d_in[8];
  const float* b0      = (const float*)d_in[9];
  const float* W_ih1   = (const float*)d_in[10];
  const float* W_hh1   = (const float*)d_in[11];
  const float* b1      = (const float*)d_in[12];
  const float* W_out   = (const float*)d_in[13];
  const float* b_out   = (const float*)d_in[14];
  float* out = (float*)d_out;

  char* ws = (char*)d_ws;
  char*  WA0    = ws;                         // Whh0 A-frags hi/lo 16MB; becomes h0 slots 1..128
  char*  WA1    = ws + 16777216;              // Wih1 (hi staged, lo streamed)
  char*  WA2    = ws + 33554432;              // Whh1
  char*  WoutB  = ws + 50331648;              // W_out B-frags, 1MB
  char*  embB   = ws + 51380224;              // emb B-frags, 1MB
  float* E0     = (float*)(ws + 52428800);    // 4MB f32
  float* b1i    = (float*)(ws + 56623104);    // 16KB
  int*   f0     = (int*)(ws + 56639488);      // PACKED flag array (128 ints)
  int*   f1     = (int*)(ws + 56643584);      // PACKED flag array (128 ints)
  char*  h0s0   = ws + 56647680;              // h0 slot 0, 128KB
  char*  h0hi   = ws + 56778752;              // h0 slots 129..256, 16MB
  char*  h1frag = ws + 73555968;              // 257 slots x 128KB (~33.7MB) -> end ~102.3MB
  char*  WAi0   = h1frag + 16777216;          // Wih0 A-frags alias h1 slots 128..255
                                              // (read via sc-loads at E0; slot 128 written step 127)

  prep_misc <<<18,   256, 0, stream>>>(b1, b1i, f0, f1);
  prep_wfrag<<<8192, 256, 0, stream>>>(W_hh0, W_ih1, W_hh1, W_ih0, WA0, WA1, WA2, WAi0);
  prep_bfrag<<<256,  256, 0, stream>>>(emb, W_out, embB, WoutB);
  prep_hinit<<<32,   256, 0, stream>>>(h0_in, h1_in, h0s0, h1frag);

  hipFuncSetAttribute(reinterpret_cast<const void*>(lstm_persist),
                      hipFuncAttributeMaxDynamicSharedMemorySize, 148480);
  lstm_persist<<<256, 256, 148480, stream>>>(
      targets, c0_in, c1_in, b0, b_out,
      WA0, WA1, WA2, WAi0, WoutB, embB,
      E0, b1i, h0s0, h0hi, h1frag, f0, f1, out);
}